// Round 5
// baseline (471.302 us; speedup 1.0000x reference)
//
#include <hip/hip_runtime.h>
#include <hip/hip_bf16.h>
#include <math.h>
#include <stdint.h>

typedef __bf16 bf16;
typedef __bf16 bf16x4 __attribute__((ext_vector_type(4)));
typedef __bf16 bf16x8 __attribute__((ext_vector_type(8)));
typedef float f32x4 __attribute__((ext_vector_type(4)));

#define MFMA16(a, b, c) __builtin_amdgcn_mfma_f32_16x16x32_bf16((a), (b), (c), 0, 0, 0)

constexpr int EMB = 1024;
constexpr int SEQ = 2048;
constexpr int BATCH = 2;
constexpr int NTOK = BATCH * SEQ;   // 4096
constexpr int FFN = 4 * EMB;        // 4096
constexpr int HEADS = 16;
constexpr int HDIM = 64;

// q pre-scale: 1/sqrt(64) * log2(e)  (softmax runs in exp2 domain)
#define QSCALE 0.18033688011112042f

// async 16B global -> LDS (wave-uniform base + lane*16 destination)
__device__ __forceinline__ void gload16(const void* g, void* l) {
    __builtin_amdgcn_global_load_lds(
        (const __attribute__((address_space(1))) void*)g,
        (__attribute__((address_space(3))) void*)l,
        16, 0, 0);
}

// ---------------- LayerNorm: fp32 in -> bf16 out --------------------------
__global__ __launch_bounds__(256) void ln_kernel(const float* __restrict__ x,
                                                 const float* __restrict__ g,
                                                 const float* __restrict__ b,
                                                 bf16* __restrict__ out) {
    int row = blockIdx.x;
    int t = threadIdx.x;
    float4 v = reinterpret_cast<const float4*>(x + (size_t)row * EMB)[t];
    float s = v.x + v.y + v.z + v.w;
    float s2 = v.x * v.x + v.y * v.y + v.z * v.z + v.w * v.w;
#pragma unroll
    for (int o = 1; o < 64; o <<= 1) {
        s += __shfl_xor(s, o);
        s2 += __shfl_xor(s2, o);
    }
    __shared__ float ps[4], ps2[4];
    int w = t >> 6;
    if ((t & 63) == 0) { ps[w] = s; ps2[w] = s2; }
    __syncthreads();
    s = ps[0] + ps[1] + ps[2] + ps[3];
    s2 = ps2[0] + ps2[1] + ps2[2] + ps2[3];
    float mean = s * (1.f / EMB);
    float var = s2 * (1.f / EMB) - mean * mean;
    float rstd = rsqrtf(var + 1e-5f);
    float4 gv = reinterpret_cast<const float4*>(g)[t];
    float4 bv = reinterpret_cast<const float4*>(b)[t];
    bf16* op = out + (size_t)row * EMB + t * 4;
    op[0] = (bf16)(gv.x * (v.x - mean) * rstd + bv.x);
    op[1] = (bf16)(gv.y * (v.y - mean) * rstd + bv.y);
    op[2] = (bf16)(gv.z * (v.z - mean) * rstd + bv.z);
    op[3] = (bf16)(gv.w * (v.w - mean) * rstd + bv.w);
}

// ---------------- transpose + cast: W[K][N] f32 -> Wt[N][K] bf16 ----------
__global__ __launch_bounds__(256) void transpose_cast(const float* __restrict__ W,
                                                      bf16* __restrict__ Wt,
                                                      int K, int N) {
    __shared__ float t[32][33];
    int n0 = blockIdx.x * 32, k0 = blockIdx.y * 32;
    int tx = threadIdx.x, ty = threadIdx.y;  // 32 x 8
#pragma unroll
    for (int i = 0; i < 4; i++)
        t[ty + 8 * i][tx] = W[(size_t)(k0 + ty + 8 * i) * N + n0 + tx];
    __syncthreads();
#pragma unroll
    for (int i = 0; i < 4; i++)
        Wt[(size_t)(n0 + ty + 8 * i) * K + k0 + tx] = (bf16)t[tx][ty + 8 * i];
}

// ---------------- V transpose: [B,H,S,64] -> [B,H,64,S] bf16 --------------
__global__ __launch_bounds__(256) void vtrans(const bf16* __restrict__ v,
                                              bf16* __restrict__ vt) {
    int bh = blockIdx.y;
    int s0 = blockIdx.x * 64;
    const bf16* src = v + (size_t)bh * SEQ * HDIM + (size_t)s0 * HDIM;
    bf16* dst = vt + (size_t)bh * HDIM * SEQ + s0;
    __shared__ bf16 tile[64][72];
    int t = threadIdx.x;
    int s = t >> 2, d0 = (t & 3) * 16;
    bf16x8 a = *reinterpret_cast<const bf16x8*>(src + s * HDIM + d0);
    bf16x8 b = *reinterpret_cast<const bf16x8*>(src + s * HDIM + d0 + 8);
#pragma unroll
    for (int e = 0; e < 8; e++) {
        tile[d0 + e][s] = a[e];
        tile[d0 + 8 + e][s] = b[e];
    }
    __syncthreads();
    int d = t >> 2, c0 = (t & 3) * 16;
    bf16x8 o0 = *reinterpret_cast<const bf16x8*>(&tile[d][c0]);
    bf16x8 o1 = *reinterpret_cast<const bf16x8*>(&tile[d][c0 + 8]);
    *reinterpret_cast<bf16x8*>(dst + (size_t)d * SEQ + c0) = o0;
    *reinterpret_cast<bf16x8*>(dst + (size_t)d * SEQ + c0 + 8) = o1;
}

// ---------------- LDS-staged GEMM (m97 structure) -------------------------
// C = epi(A[M][K] @ Bt[N][K]^T), BK=32, 4 waves in 2x2, per-wave (BM/2)x(BN/2)
// MODE 0: fused QKV scatter -> bf16 q/k/v [B,H,S,64] (q scaled QSCALE)
// MODE 1: out f32 = resid + acc + bias
// MODE 2: out bf16 = gelu(acc + bias)
template <int BM, int BN, int MODE>
__global__ __launch_bounds__(256) void gemm_lds(const bf16* __restrict__ A,
                                                const bf16* __restrict__ Bt,
                                                int M, int N, int K,
                                                float* __restrict__ outF,
                                                bf16* __restrict__ outB,
                                                const float* __restrict__ bias,
                                                const float* __restrict__ resid) {
    constexpr int MR = BM / 32;              // M frags per wave
    constexpr int NR = BN / 32;              // N frags per wave
    constexpr int ACH = (BM * 64) / 4096;    // 16B chunks/thread for A tile
    constexpr int BCH = (BN * 64) / 4096;
    __shared__ bf16 sA[BM * 32];
    __shared__ bf16 sB[BN * 32];
    int t = threadIdx.x;
    int wave = t >> 6, lane = t & 63;
    int wr = wave >> 1, wc = wave & 1;
    int lr = lane & 15, lg = lane >> 4;
    int row0 = blockIdx.x * BM;
    int col0 = blockIdx.y * BN;

    // staging source pointers (advance 64B per K-step)
    const char* aS[ACH];
    const char* bS[BCH];
#pragma unroll
    for (int c = 0; c < ACH; c++) {
        int o = (t + c * 256) * 16;
        aS[c] = (const char*)A + (size_t)(row0 + (o >> 6)) * K * 2 + (o & 63);
    }
#pragma unroll
    for (int c = 0; c < BCH; c++) {
        int o = (t + c * 256) * 16;
        bS[c] = (const char*)Bt + (size_t)(col0 + (o >> 6)) * K * 2 + (o & 63);
    }

    f32x4 acc[MR][NR];
#pragma unroll
    for (int m = 0; m < MR; m++)
#pragma unroll
        for (int n = 0; n < NR; n++) acc[m][n] = f32x4{0.f, 0.f, 0.f, 0.f};

    for (int k0 = 0; k0 < K; k0 += 32) {
        __syncthreads();
#pragma unroll
        for (int c = 0; c < ACH; c++)
            gload16(aS[c], (char*)sA + (t + c * 256) * 16);
#pragma unroll
        for (int c = 0; c < BCH; c++)
            gload16(bS[c], (char*)sB + (t + c * 256) * 16);
#pragma unroll
        for (int c = 0; c < ACH; c++) aS[c] += 64;
#pragma unroll
        for (int c = 0; c < BCH; c++) bS[c] += 64;
        __syncthreads();

        bf16x8 a[MR], b[NR];
#pragma unroll
        for (int m = 0; m < MR; m++)
            a[m] = *reinterpret_cast<const bf16x8*>(
                sA + (wr * (BM / 2) + m * 16 + lr) * 32 + 8 * lg);
#pragma unroll
        for (int n = 0; n < NR; n++)
            b[n] = *reinterpret_cast<const bf16x8*>(
                sB + (wc * (BN / 2) + n * 16 + lr) * 32 + 8 * lg);
#pragma unroll
        for (int m = 0; m < MR; m++)
#pragma unroll
            for (int n = 0; n < NR; n++)
                acc[m][n] = MFMA16(a[m], b[n], acc[m][n]);
    }

#pragma unroll
    for (int m = 0; m < MR; m++) {
#pragma unroll
        for (int r = 0; r < 4; r++) {
            int row = row0 + wr * (BM / 2) + m * 16 + 4 * lg + r;
#pragma unroll
            for (int n = 0; n < NR; n++) {
                int col = col0 + wc * (BN / 2) + n * 16 + lr;
                float v = acc[m][n][r];
                if (MODE == 0) {
                    int b_ = row >> 11, s_ = row & 2047;
                    int which = col >> 10, rem = col & 1023;
                    int h_ = rem >> 6, d_ = rem & 63;
                    float sc = (which == 0) ? QSCALE : 1.0f;
                    outB[(size_t)which * (NTOK * EMB) +
                         (((size_t)(b_ * HEADS + h_) * SEQ + s_) << 6) + d_] =
                        (bf16)(v * sc);
                } else if (MODE == 1) {
                    size_t idx = (size_t)row * N + col;
                    outF[idx] = resid[idx] + v + bias[col];
                } else {
                    float u = v + bias[col];
                    float gl = 0.5f * u *
                               (1.f + tanhf(0.7978845608028654f *
                                            (u + 0.044715f * u * u * u)));
                    outB[(size_t)row * N + col] = (bf16)gl;
                }
            }
        }
    }
}

// ---------------- causal flash attention ----------------------------------
// Swapped-QK^T (lane owns one q-row) + register K/V prefetch.
// q,k: [B,H,S,64] bf16 (q pre-scaled by QSCALE); vt: [B,H,64,S] bf16
// ctx out: [B,S,H*64] bf16. 4 waves/block, 16 q-rows/wave, barrier-free.
// Grid: 1024 blocks, XCD-bijective swizzle (each XCD owns 4 whole heads).
__global__ __launch_bounds__(256, 4) void attn_kernel(const bf16* __restrict__ q,
                                                      const bf16* __restrict__ k,
                                                      const bf16* __restrict__ vt,
                                                      bf16* __restrict__ ctx) {
    int wg = blockIdx.x;
    int wgid = (wg & 7) * 128 + (wg >> 3);   // bijective: 1024 = 8 XCD * 128
    int bh = wgid >> 5;                      // 4 heads per XCD, contiguous
    int q0 = (31 - (wgid & 31)) * 64;        // late (heavy) q-blocks first
    const bf16* qh = q + (size_t)bh * SEQ * HDIM;
    const bf16* kh = k + (size_t)bh * SEQ * HDIM;
    const bf16* vh = vt + (size_t)bh * HDIM * SEQ;  // [64][2048]
    int wave = threadIdx.x >> 6, lane = threadIdx.x & 63;
    int lr = lane & 15, lg = lane >> 4;
    int qrow = q0 + wave * 16;

    __shared__ bf16 plds[4][16][72];  // per-wave P[q][key], padded stride

    bf16x8 qf0 = *reinterpret_cast<const bf16x8*>(qh + (size_t)(qrow + lr) * HDIM + 8 * lg);
    bf16x8 qf1 = *reinterpret_cast<const bf16x8*>(qh + (size_t)(qrow + lr) * HDIM + 32 + 8 * lg);

    f32x4 o[4];
#pragma unroll
    for (int n = 0; n < 4; n++) o[n] = f32x4{0.f, 0.f, 0.f, 0.f};
    float mx = -1e30f, lsum = 0.f;  // per-lane state for q-row = qrow + lr

    int kend = q0 + 64;

    // preload K frags for chunk 0
    bf16x8 kf[4][2];
#pragma unroll
    for (int n = 0; n < 4; n++) {
        const bf16* kp = kh + (size_t)(n * 16 + lr) * HDIM + 8 * lg;
        kf[n][0] = *reinterpret_cast<const bf16x8*>(kp);
        kf[n][1] = *reinterpret_cast<const bf16x8*>(kp + 32);
    }

    for (int c0 = 0; c0 < kend; c0 += 64) {
        // ---- QK^T swapped: st = S^T frag, lane holds key=4lg+r+16n, q=lr ----
        f32x4 st[4];
#pragma unroll
        for (int n = 0; n < 4; n++) {
            f32x4 tAcc = f32x4{0.f, 0.f, 0.f, 0.f};
            tAcc = MFMA16(kf[n][0], qf0, tAcc);
            tAcc = MFMA16(kf[n][1], qf1, tAcc);
            st[n] = tAcc;
        }

        // ---- prefetch next chunk's K into kf (hidden under softmax) ----
        int cn = c0 + 64;
        if (cn >= kend) cn = kend - 64;
#pragma unroll
        for (int n = 0; n < 4; n++) {
            const bf16* kp = kh + (size_t)(cn + n * 16 + lr) * HDIM + 8 * lg;
            kf[n][0] = *reinterpret_cast<const bf16x8*>(kp);
            kf[n][1] = *reinterpret_cast<const bf16x8*>(kp + 32);
        }
        // ---- prefetch this chunk's V frags ----
        bf16x8 vf[4][2];
#pragma unroll
        for (int n = 0; n < 4; n++)
#pragma unroll
            for (int ks = 0; ks < 2; ks++)
                vf[n][ks] = *reinterpret_cast<const bf16x8*>(
                    vh + (size_t)(n * 16 + lr) * SEQ + c0 + ks * 32 + 8 * lg);

        if (c0 == q0) {  // diagonal chunk: causal mask (key > q)
#pragma unroll
            for (int n = 0; n < 4; n++)
#pragma unroll
                for (int r = 0; r < 4; r++)
                    if (c0 + n * 16 + 4 * lg + r > qrow + lr) st[n][r] = -1e30f;
        }

        // ---- softmax, per-lane row (q = lr), exp2 domain ----
        float pmax = st[0][0];
#pragma unroll
        for (int n = 0; n < 4; n++)
#pragma unroll
            for (int r = 0; r < 4; r++) pmax = fmaxf(pmax, st[n][r]);
        pmax = fmaxf(pmax, __shfl_xor(pmax, 16));
        pmax = fmaxf(pmax, __shfl_xor(pmax, 32));
        float mn = fmaxf(mx, pmax);
        float scl = __builtin_amdgcn_exp2f(mx - mn);
        mx = mn;
        float ps = 0.f;
#pragma unroll
        for (int n = 0; n < 4; n++) {
            float p0 = __builtin_amdgcn_exp2f(st[n][0] - mn);
            float p1 = __builtin_amdgcn_exp2f(st[n][1] - mn);
            float p2 = __builtin_amdgcn_exp2f(st[n][2] - mn);
            float p3 = __builtin_amdgcn_exp2f(st[n][3] - mn);
            ps += (p0 + p1) + (p2 + p3);
            bf16x4 pv = {(bf16)p0, (bf16)p1, (bf16)p2, (bf16)p3};
            *reinterpret_cast<bf16x4*>(&plds[wave][lr][n * 16 + 4 * lg]) = pv;
        }
        ps += __shfl_xor(ps, 16);
        ps += __shfl_xor(ps, 32);
        lsum = lsum * scl + ps;

        // ---- rescale o (scl broadcast from lane owning row 4lg+r) ----
        int sbase = 20 * lg;  // (lg<<4) | (4*lg) : lane with lr = 4*lg+r
        float s0 = __shfl(scl, sbase + 0);
        float s1 = __shfl(scl, sbase + 1);
        float s2 = __shfl(scl, sbase + 2);
        float s3 = __shfl(scl, sbase + 3);
#pragma unroll
        for (int n = 0; n < 4; n++) {
            o[n][0] *= s0; o[n][1] *= s1; o[n][2] *= s2; o[n][3] *= s3;
        }

        // ---- PV: pa from per-wave LDS, V from regs ----
#pragma unroll
        for (int ks = 0; ks < 2; ks++) {
            bf16x8 pa = *reinterpret_cast<const bf16x8*>(
                &plds[wave][lr][ks * 32 + 8 * lg]);
#pragma unroll
            for (int n = 0; n < 4; n++) o[n] = MFMA16(pa, vf[n][ks], o[n]);
        }
    }

    float inv = 1.f / lsum;
    int sbase = 20 * lg;
    float i0 = __shfl(inv, sbase + 0);
    float i1 = __shfl(inv, sbase + 1);
    float i2 = __shfl(inv, sbase + 2);
    float i3 = __shfl(inv, sbase + 3);
    float iv[4] = {i0, i1, i2, i3};

    int b_ = bh >> 4, h_ = bh & 15;
#pragma unroll
    for (int r = 0; r < 4; r++) {
        int srow = qrow + 4 * lg + r;
        size_t base = ((size_t)b_ * SEQ + srow) * EMB + h_ * HDIM;
#pragma unroll
        for (int n = 0; n < 4; n++)
            ctx[base + n * 16 + lr] = (bf16)(o[n][r] * iv[r]);
    }
}

// ---------------- launch ---------------------------------------------------
extern "C" void kernel_launch(void* const* d_in, const int* in_sizes, int n_in,
                              void* d_out, int out_size, void* d_ws, size_t ws_size,
                              hipStream_t stream) {
    const float* x  = (const float*)d_in[0];
    const float* Wq = (const float*)d_in[1];
    const float* Wk = (const float*)d_in[2];
    const float* Wv = (const float*)d_in[3];
    const float* Wo = (const float*)d_in[4];
    const float* bo = (const float*)d_in[5];
    const float* W1 = (const float*)d_in[6];
    const float* b1 = (const float*)d_in[7];
    const float* W2 = (const float*)d_in[8];
    const float* b2 = (const float*)d_in[9];
    const float* g1 = (const float*)d_in[10];
    const float* s1 = (const float*)d_in[11];
    const float* g2 = (const float*)d_in[12];
    const float* s2 = (const float*)d_in[13];

    const size_t MB = 1ull << 20;
    char* w = (char*)d_ws;
    bf16* Wqkvt = (bf16*)(w + 0 * MB);            // [3072][1024] contiguous
    bf16* Wqt = Wqkvt;
    bf16* Wkt = (bf16*)(w + 2 * MB);
    bf16* Wvt = (bf16*)(w + 4 * MB);
    bf16* Wot = (bf16*)(w + 6 * MB);
    bf16* W1t = (bf16*)(w + 8 * MB);
    bf16* W2t = (bf16*)(w + 16 * MB);
    bf16* hbuf = (bf16*)(w + 24 * MB);            // h1 / h2 (reused)
    bf16* vtb  = (bf16*)(w + 24 * MB);            // aliases hbuf: used between QKV and LN2
    bf16* qkvb = (bf16*)(w + 32 * MB);            // q @32, k @40, v @48 MB
    bf16* qb   = (bf16*)(w + 32 * MB);
    bf16* kb   = (bf16*)(w + 40 * MB);
    bf16* vb   = (bf16*)(w + 48 * MB);
    bf16* ctxb = (bf16*)(w + 56 * MB);
    bf16* midb = (bf16*)(w + 32 * MB);            // reuses qkv after attn
    float* x1  = (float*)(w + 64 * MB);

    dim3 tb(32, 8);
    // weight transposes (fp32 -> bf16 [N][K]); Wq/Wk/Wv contiguous
    transpose_cast<<<dim3(EMB / 32, EMB / 32), tb, 0, stream>>>(Wq, Wqt, EMB, EMB);
    transpose_cast<<<dim3(EMB / 32, EMB / 32), tb, 0, stream>>>(Wk, Wkt, EMB, EMB);
    transpose_cast<<<dim3(EMB / 32, EMB / 32), tb, 0, stream>>>(Wv, Wvt, EMB, EMB);
    transpose_cast<<<dim3(EMB / 32, EMB / 32), tb, 0, stream>>>(Wo, Wot, EMB, EMB);
    transpose_cast<<<dim3(FFN / 32, EMB / 32), tb, 0, stream>>>(W1, W1t, EMB, FFN);
    transpose_cast<<<dim3(EMB / 32, FFN / 32), tb, 0, stream>>>(W2, W2t, FFN, EMB);

    // LN1
    ln_kernel<<<NTOK, 256, 0, stream>>>(x, g1, s1, hbuf);

    // fused QKV projection: [4096,1024] @ [3072,1024]^T
    gemm_lds<128, 128, 0><<<dim3(NTOK / 128, 3072 / 128), 256, 0, stream>>>(
        hbuf, Wqkvt, NTOK, 3072, EMB, nullptr, qkvb, nullptr, nullptr);

    // V -> V^T  [B,H,64,S]  (hbuf region is free until LN2)
    vtrans<<<dim3(SEQ / 64, BATCH * HEADS), 256, 0, stream>>>(vb, vtb);

    // attention (swapped-QK^T, reg prefetch, XCD-swizzled)
    attn_kernel<<<dim3(SEQ / 64 * BATCH * HEADS), 256, 0, stream>>>(qb, kb, vtb, ctxb);

    // output projection + residual -> x1 (f32)
    gemm_lds<128, 64, 1><<<dim3(NTOK / 128, EMB / 64), 256, 0, stream>>>(
        ctxb, Wot, NTOK, EMB, EMB, x1, nullptr, bo, x);

    // LN2
    ln_kernel<<<NTOK, 256, 0, stream>>>(x1, g2, s2, hbuf);

    // FFN1 + gelu -> bf16 mid
    gemm_lds<128, 128, 2><<<dim3(NTOK / 128, FFN / 128), 256, 0, stream>>>(
        hbuf, W1t, NTOK, FFN, EMB, nullptr, midb, b1, nullptr);

    // FFN2 + bias + residual -> d_out (f32)
    gemm_lds<128, 64, 1><<<dim3(NTOK / 128, EMB / 64), 256, 0, stream>>>(
        midb, W2t, NTOK, EMB, FFN, (float*)d_out, nullptr, b2, x1);
}

// Round 6
// 468.365 us; speedup vs baseline: 1.0063x; 1.0063x over previous
//
#include <hip/hip_runtime.h>
#include <hip/hip_bf16.h>
#include <math.h>
#include <stdint.h>

typedef __bf16 bf16;
typedef __bf16 bf16x4 __attribute__((ext_vector_type(4)));
typedef __bf16 bf16x8 __attribute__((ext_vector_type(8)));
typedef float f32x4 __attribute__((ext_vector_type(4)));

#define MFMA16(a, b, c) __builtin_amdgcn_mfma_f32_16x16x32_bf16((a), (b), (c), 0, 0, 0)

constexpr int EMB = 1024;
constexpr int SEQ = 2048;
constexpr int BATCH = 2;
constexpr int NTOK = BATCH * SEQ;   // 4096
constexpr int FFN = 4 * EMB;        // 4096
constexpr int HEADS = 16;
constexpr int HDIM = 64;

// q pre-scale: 1/sqrt(64) * log2(e)  (softmax runs in exp2 domain)
#define QSCALE 0.18033688011112042f

// async 16B global -> LDS (wave-uniform base + lane*16 destination)
__device__ __forceinline__ void gload16(const void* g, void* l) {
    __builtin_amdgcn_global_load_lds(
        (const __attribute__((address_space(1))) void*)g,
        (__attribute__((address_space(3))) void*)l,
        16, 0, 0);
}

// ---------------- LayerNorm: fp32 in -> bf16 out --------------------------
__global__ __launch_bounds__(256) void ln_kernel(const float* __restrict__ x,
                                                 const float* __restrict__ g,
                                                 const float* __restrict__ b,
                                                 bf16* __restrict__ out) {
    int row = blockIdx.x;
    int t = threadIdx.x;
    float4 v = reinterpret_cast<const float4*>(x + (size_t)row * EMB)[t];
    float s = v.x + v.y + v.z + v.w;
    float s2 = v.x * v.x + v.y * v.y + v.z * v.z + v.w * v.w;
#pragma unroll
    for (int o = 1; o < 64; o <<= 1) {
        s += __shfl_xor(s, o);
        s2 += __shfl_xor(s2, o);
    }
    __shared__ float ps[4], ps2[4];
    int w = t >> 6;
    if ((t & 63) == 0) { ps[w] = s; ps2[w] = s2; }
    __syncthreads();
    s = ps[0] + ps[1] + ps[2] + ps[3];
    s2 = ps2[0] + ps2[1] + ps2[2] + ps2[3];
    float mean = s * (1.f / EMB);
    float var = s2 * (1.f / EMB) - mean * mean;
    float rstd = rsqrtf(var + 1e-5f);
    float4 gv = reinterpret_cast<const float4*>(g)[t];
    float4 bv = reinterpret_cast<const float4*>(b)[t];
    bf16* op = out + (size_t)row * EMB + t * 4;
    op[0] = (bf16)(gv.x * (v.x - mean) * rstd + bv.x);
    op[1] = (bf16)(gv.y * (v.y - mean) * rstd + bv.y);
    op[2] = (bf16)(gv.z * (v.z - mean) * rstd + bv.z);
    op[3] = (bf16)(gv.w * (v.w - mean) * rstd + bv.w);
}

// ---------------- transpose + cast: W[K][N] f32 -> Wt[N][K] bf16 ----------
__global__ __launch_bounds__(256) void transpose_cast(const float* __restrict__ W,
                                                      bf16* __restrict__ Wt,
                                                      int K, int N) {
    __shared__ float t[32][33];
    int n0 = blockIdx.x * 32, k0 = blockIdx.y * 32;
    int tx = threadIdx.x, ty = threadIdx.y;  // 32 x 8
#pragma unroll
    for (int i = 0; i < 4; i++)
        t[ty + 8 * i][tx] = W[(size_t)(k0 + ty + 8 * i) * N + n0 + tx];
    __syncthreads();
#pragma unroll
    for (int i = 0; i < 4; i++)
        Wt[(size_t)(n0 + ty + 8 * i) * K + k0 + tx] = (bf16)t[tx][ty + 8 * i];
}

// ---------------- V transpose: [B,H,S,64] -> [B,H,64,S] bf16 --------------
__global__ __launch_bounds__(256) void vtrans(const bf16* __restrict__ v,
                                              bf16* __restrict__ vt) {
    int bh = blockIdx.y;
    int s0 = blockIdx.x * 64;
    const bf16* src = v + (size_t)bh * SEQ * HDIM + (size_t)s0 * HDIM;
    bf16* dst = vt + (size_t)bh * HDIM * SEQ + s0;
    __shared__ bf16 tile[64][72];
    int t = threadIdx.x;
    int s = t >> 2, d0 = (t & 3) * 16;
    bf16x8 a = *reinterpret_cast<const bf16x8*>(src + s * HDIM + d0);
    bf16x8 b = *reinterpret_cast<const bf16x8*>(src + s * HDIM + d0 + 8);
#pragma unroll
    for (int e = 0; e < 8; e++) {
        tile[d0 + e][s] = a[e];
        tile[d0 + 8 + e][s] = b[e];
    }
    __syncthreads();
    int d = t >> 2, c0 = (t & 3) * 16;
    bf16x8 o0 = *reinterpret_cast<const bf16x8*>(&tile[d][c0]);
    bf16x8 o1 = *reinterpret_cast<const bf16x8*>(&tile[d][c0 + 8]);
    *reinterpret_cast<bf16x8*>(dst + (size_t)d * SEQ + c0) = o0;
    *reinterpret_cast<bf16x8*>(dst + (size_t)d * SEQ + c0 + 8) = o1;
}

// ---------------- LDS-staged GEMM (m97 structure) -------------------------
// C = epi(A[M][K] @ Bt[N][K]^T), BK=32, 4 waves in 2x2, per-wave (BM/2)x(BN/2)
// MODE 0: fused QKV scatter -> bf16 q/k/v [B,H,S,64] (q scaled QSCALE)
// MODE 1: out f32 = resid + acc + bias
// MODE 2: out bf16 = gelu(acc + bias)
template <int BM, int BN, int MODE>
__global__ __launch_bounds__(256) void gemm_lds(const bf16* __restrict__ A,
                                                const bf16* __restrict__ Bt,
                                                int M, int N, int K,
                                                float* __restrict__ outF,
                                                bf16* __restrict__ outB,
                                                const float* __restrict__ bias,
                                                const float* __restrict__ resid) {
    constexpr int MR = BM / 32;              // M frags per wave
    constexpr int NR = BN / 32;              // N frags per wave
    constexpr int ACH = (BM * 64) / 4096;    // 16B chunks/thread for A tile
    constexpr int BCH = (BN * 64) / 4096;
    __shared__ bf16 sA[BM * 32];
    __shared__ bf16 sB[BN * 32];
    int t = threadIdx.x;
    int wave = t >> 6, lane = t & 63;
    int wr = wave >> 1, wc = wave & 1;
    int lr = lane & 15, lg = lane >> 4;
    int row0 = blockIdx.x * BM;
    int col0 = blockIdx.y * BN;

    // staging source pointers (advance 64B per K-step)
    const char* aS[ACH];
    const char* bS[BCH];
#pragma unroll
    for (int c = 0; c < ACH; c++) {
        int o = (t + c * 256) * 16;
        aS[c] = (const char*)A + (size_t)(row0 + (o >> 6)) * K * 2 + (o & 63);
    }
#pragma unroll
    for (int c = 0; c < BCH; c++) {
        int o = (t + c * 256) * 16;
        bS[c] = (const char*)Bt + (size_t)(col0 + (o >> 6)) * K * 2 + (o & 63);
    }

    f32x4 acc[MR][NR];
#pragma unroll
    for (int m = 0; m < MR; m++)
#pragma unroll
        for (int n = 0; n < NR; n++) acc[m][n] = f32x4{0.f, 0.f, 0.f, 0.f};

    for (int k0 = 0; k0 < K; k0 += 32) {
        __syncthreads();
#pragma unroll
        for (int c = 0; c < ACH; c++)
            gload16(aS[c], (char*)sA + (t + c * 256) * 16);
#pragma unroll
        for (int c = 0; c < BCH; c++)
            gload16(bS[c], (char*)sB + (t + c * 256) * 16);
#pragma unroll
        for (int c = 0; c < ACH; c++) aS[c] += 64;
#pragma unroll
        for (int c = 0; c < BCH; c++) bS[c] += 64;
        __syncthreads();

        bf16x8 a[MR], b[NR];
#pragma unroll
        for (int m = 0; m < MR; m++)
            a[m] = *reinterpret_cast<const bf16x8*>(
                sA + (wr * (BM / 2) + m * 16 + lr) * 32 + 8 * lg);
#pragma unroll
        for (int n = 0; n < NR; n++)
            b[n] = *reinterpret_cast<const bf16x8*>(
                sB + (wc * (BN / 2) + n * 16 + lr) * 32 + 8 * lg);
#pragma unroll
        for (int m = 0; m < MR; m++)
#pragma unroll
            for (int n = 0; n < NR; n++)
                acc[m][n] = MFMA16(a[m], b[n], acc[m][n]);
    }

#pragma unroll
    for (int m = 0; m < MR; m++) {
#pragma unroll
        for (int r = 0; r < 4; r++) {
            int row = row0 + wr * (BM / 2) + m * 16 + 4 * lg + r;
#pragma unroll
            for (int n = 0; n < NR; n++) {
                int col = col0 + wc * (BN / 2) + n * 16 + lr;
                float v = acc[m][n][r];
                if (MODE == 0) {
                    int b_ = row >> 11, s_ = row & 2047;
                    int which = col >> 10, rem = col & 1023;
                    int h_ = rem >> 6, d_ = rem & 63;
                    float sc = (which == 0) ? QSCALE : 1.0f;
                    outB[(size_t)which * (NTOK * EMB) +
                         (((size_t)(b_ * HEADS + h_) * SEQ + s_) << 6) + d_] =
                        (bf16)(v * sc);
                } else if (MODE == 1) {
                    size_t idx = (size_t)row * N + col;
                    outF[idx] = resid[idx] + v + bias[col];
                } else {
                    float u = v + bias[col];
                    float gl = 0.5f * u *
                               (1.f + tanhf(0.7978845608028654f *
                                            (u + 0.044715f * u * u * u)));
                    outB[(size_t)row * N + col] = (bf16)gl;
                }
            }
        }
    }
}

// ---------------- causal flash attention ----------------------------------
// Swapped-QK^T + swapped-PV: all softmax state is per-lane (q = lr), zero
// cross-lane broadcasts; only 2+2 xor16/32 reduces per 128-key chunk.
// q,k: [B,H,S,64] bf16 (q pre-scaled by QSCALE); vt: [B,H,64,S] bf16
// ctx out: [B,S,H*64] bf16. 8 waves/block, 16 q-rows/wave, 128-row q-block,
// KVBLK=128, barrier-free. Grid 512, XCD-bijective swizzle (4 heads/XCD).
__global__ __launch_bounds__(512, 4) void attn_kernel(const bf16* __restrict__ q,
                                                      const bf16* __restrict__ k,
                                                      const bf16* __restrict__ vt,
                                                      bf16* __restrict__ ctx) {
    int wg = blockIdx.x;
    int wgid = (wg & 7) * 64 + (wg >> 3);   // bijective: 512 = 8 XCD * 64
    int bh = wgid >> 4;                     // 16 blocks/head -> 4 heads/XCD
    int q0 = (15 - (wgid & 15)) * 128;      // late (heavy) q-blocks first
    const bf16* qh = q + (size_t)bh * SEQ * HDIM;
    const bf16* kh = k + (size_t)bh * SEQ * HDIM;
    const bf16* vh = vt + (size_t)bh * HDIM * SEQ;  // [64][2048]
    int wave = threadIdx.x >> 6, lane = threadIdx.x & 63;
    int lr = lane & 15, lg = lane >> 4;
    int qrow = q0 + wave * 16;

    // per-wave P[q=16][key=128], row stride 152 (304B = 12 dwords mod 32:
    // conflict-free b64 writes, 2-way (free) b128 reads, 16B-aligned)
    __shared__ bf16 plds[8][16][152];

    bf16x8 qf0 = *reinterpret_cast<const bf16x8*>(qh + (size_t)(qrow + lr) * HDIM + 8 * lg);
    bf16x8 qf1 = *reinterpret_cast<const bf16x8*>(qh + (size_t)(qrow + lr) * HDIM + 32 + 8 * lg);

    f32x4 o[4];
#pragma unroll
    for (int n = 0; n < 4; n++) o[n] = f32x4{0.f, 0.f, 0.f, 0.f};
    float mx = -1e30f, lsum = 0.f;  // per-lane state for q-row = qrow + lr

    for (int c0 = 0; c0 <= q0; c0 += 128) {
        // ---- QK^T swapped: st[n] holds S^T, lane: key=c0+16n+4lg+r, q=lr ----
        f32x4 st[8];
#pragma unroll
        for (int n = 0; n < 8; n++) {
            const bf16* kp = kh + (size_t)(c0 + n * 16 + lr) * HDIM + 8 * lg;
            bf16x8 kf0 = *reinterpret_cast<const bf16x8*>(kp);
            bf16x8 kf1 = *reinterpret_cast<const bf16x8*>(kp + 32);
            f32x4 tAcc = f32x4{0.f, 0.f, 0.f, 0.f};
            tAcc = MFMA16(kf0, qf0, tAcc);
            tAcc = MFMA16(kf1, qf1, tAcc);
            st[n] = tAcc;
        }

        if (c0 == q0) {  // diagonal chunk: causal mask (key > q)
#pragma unroll
            for (int n = 0; n < 8; n++)
#pragma unroll
                for (int r = 0; r < 4; r++)
                    if (c0 + n * 16 + 4 * lg + r > qrow + lr) st[n][r] = -1e30f;
        }

        // ---- softmax, per-lane row (q = lr), exp2 domain ----
        float pmax = mx;
#pragma unroll
        for (int n = 0; n < 8; n++)
#pragma unroll
            for (int r = 0; r < 4; r++) pmax = fmaxf(pmax, st[n][r]);
        pmax = fmaxf(pmax, __shfl_xor(pmax, 16));
        pmax = fmaxf(pmax, __shfl_xor(pmax, 32));
        float mn = pmax;
        float scl = __builtin_amdgcn_exp2f(mx - mn);
        mx = mn;
        float ps = 0.f;
#pragma unroll
        for (int n = 0; n < 8; n++) {
            float p0 = __builtin_amdgcn_exp2f(st[n][0] - mn);
            float p1 = __builtin_amdgcn_exp2f(st[n][1] - mn);
            float p2 = __builtin_amdgcn_exp2f(st[n][2] - mn);
            float p3 = __builtin_amdgcn_exp2f(st[n][3] - mn);
            ps += (p0 + p1) + (p2 + p3);
            bf16x4 pv = {(bf16)p0, (bf16)p1, (bf16)p2, (bf16)p3};
            *reinterpret_cast<bf16x4*>(&plds[wave][lr][n * 16 + 4 * lg]) = pv;
        }
        ps += __shfl_xor(ps, 16);
        ps += __shfl_xor(ps, 32);
        lsum = lsum * scl + ps;

        // ---- rescale o: scl is per-lane (o cols = q = lr), no broadcast ----
#pragma unroll
        for (int n = 0; n < 4; n++) {
            o[n][0] *= scl; o[n][1] *= scl; o[n][2] *= scl; o[n][3] *= scl;
        }

        // ---- PV swapped: o^T[d][q] = V^T-frags (A) x P-frags (B) ----
#pragma unroll
        for (int ks = 0; ks < 4; ks++) {
            bf16x8 pb = *reinterpret_cast<const bf16x8*>(
                &plds[wave][lr][ks * 32 + 8 * lg]);
#pragma unroll
            for (int n = 0; n < 4; n++) {
                bf16x8 vf = *reinterpret_cast<const bf16x8*>(
                    vh + (size_t)(n * 16 + lr) * SEQ + c0 + ks * 32 + 8 * lg);
                o[n] = MFMA16(vf, pb, o[n]);
            }
        }
    }

    // ---- epilogue: per-lane normalize (q = lr), d = 16n + 4lg + r ----
    float inv = 1.f / lsum;
    int b_ = bh >> 4, h_ = bh & 15;
    size_t base = ((size_t)b_ * SEQ + qrow + lr) * EMB + h_ * HDIM;
#pragma unroll
    for (int n = 0; n < 4; n++) {
        bf16x4 pv = {(bf16)(o[n][0] * inv), (bf16)(o[n][1] * inv),
                     (bf16)(o[n][2] * inv), (bf16)(o[n][3] * inv)};
        *reinterpret_cast<bf16x4*>(ctx + base + n * 16 + 4 * lg) = pv;
    }
}

// ---------------- launch ---------------------------------------------------
extern "C" void kernel_launch(void* const* d_in, const int* in_sizes, int n_in,
                              void* d_out, int out_size, void* d_ws, size_t ws_size,
                              hipStream_t stream) {
    const float* x  = (const float*)d_in[0];
    const float* Wq = (const float*)d_in[1];
    const float* Wk = (const float*)d_in[2];
    const float* Wv = (const float*)d_in[3];
    const float* Wo = (const float*)d_in[4];
    const float* bo = (const float*)d_in[5];
    const float* W1 = (const float*)d_in[6];
    const float* b1 = (const float*)d_in[7];
    const float* W2 = (const float*)d_in[8];
    const float* b2 = (const float*)d_in[9];
    const float* g1 = (const float*)d_in[10];
    const float* s1 = (const float*)d_in[11];
    const float* g2 = (const float*)d_in[12];
    const float* s2 = (const float*)d_in[13];

    const size_t MB = 1ull << 20;
    char* w = (char*)d_ws;
    bf16* Wqkvt = (bf16*)(w + 0 * MB);            // [3072][1024] contiguous
    bf16* Wqt = Wqkvt;
    bf16* Wkt = (bf16*)(w + 2 * MB);
    bf16* Wvt = (bf16*)(w + 4 * MB);
    bf16* Wot = (bf16*)(w + 6 * MB);
    bf16* W1t = (bf16*)(w + 8 * MB);
    bf16* W2t = (bf16*)(w + 16 * MB);
    bf16* hbuf = (bf16*)(w + 24 * MB);            // h1 / h2 (reused)
    bf16* vtb  = (bf16*)(w + 24 * MB);            // aliases hbuf: used between QKV and LN2
    bf16* qkvb = (bf16*)(w + 32 * MB);            // q @32, k @40, v @48 MB
    bf16* qb   = (bf16*)(w + 32 * MB);
    bf16* kb   = (bf16*)(w + 40 * MB);
    bf16* vb   = (bf16*)(w + 48 * MB);
    bf16* ctxb = (bf16*)(w + 56 * MB);
    bf16* midb = (bf16*)(w + 32 * MB);            // reuses qkv after attn
    float* x1  = (float*)(w + 64 * MB);

    dim3 tb(32, 8);
    // weight transposes (fp32 -> bf16 [N][K]); Wq/Wk/Wv contiguous
    transpose_cast<<<dim3(EMB / 32, EMB / 32), tb, 0, stream>>>(Wq, Wqt, EMB, EMB);
    transpose_cast<<<dim3(EMB / 32, EMB / 32), tb, 0, stream>>>(Wk, Wkt, EMB, EMB);
    transpose_cast<<<dim3(EMB / 32, EMB / 32), tb, 0, stream>>>(Wv, Wvt, EMB, EMB);
    transpose_cast<<<dim3(EMB / 32, EMB / 32), tb, 0, stream>>>(Wo, Wot, EMB, EMB);
    transpose_cast<<<dim3(FFN / 32, EMB / 32), tb, 0, stream>>>(W1, W1t, EMB, FFN);
    transpose_cast<<<dim3(EMB / 32, FFN / 32), tb, 0, stream>>>(W2, W2t, FFN, EMB);

    // LN1
    ln_kernel<<<NTOK, 256, 0, stream>>>(x, g1, s1, hbuf);

    // fused QKV projection: [4096,1024] @ [3072,1024]^T
    gemm_lds<128, 128, 0><<<dim3(NTOK / 128, 3072 / 128), 256, 0, stream>>>(
        hbuf, Wqkvt, NTOK, 3072, EMB, nullptr, qkvb, nullptr, nullptr);

    // V -> V^T  [B,H,64,S]  (hbuf region is free until LN2)
    vtrans<<<dim3(SEQ / 64, BATCH * HEADS), 256, 0, stream>>>(vb, vtb);

    // attention (swapped QK^T + swapped PV, KVBLK=128, XCD-swizzled)
    attn_kernel<<<dim3(512), 512, 0, stream>>>(qb, kb, vtb, ctxb);

    // output projection + residual -> x1 (f32)
    gemm_lds<128, 64, 1><<<dim3(NTOK / 128, EMB / 64), 256, 0, stream>>>(
        ctxb, Wot, NTOK, EMB, EMB, x1, nullptr, bo, x);

    // LN2
    ln_kernel<<<NTOK, 256, 0, stream>>>(x1, g2, s2, hbuf);

    // FFN1 + gelu -> bf16 mid
    gemm_lds<128, 128, 2><<<dim3(NTOK / 128, FFN / 128), 256, 0, stream>>>(
        hbuf, W1t, NTOK, FFN, EMB, nullptr, midb, b1, nullptr);

    // FFN2 + bias + residual -> d_out (f32)
    gemm_lds<128, 64, 1><<<dim3(NTOK / 128, EMB / 64), 256, 0, stream>>>(
        midb, W2t, NTOK, EMB, FFN, (float*)d_out, nullptr, b2, x1);
}

// Round 7
// 320.667 us; speedup vs baseline: 1.4698x; 1.4606x over previous
//
#include <hip/hip_runtime.h>
#include <hip/hip_bf16.h>
#include <math.h>
#include <stdint.h>

typedef __bf16 bf16;
typedef __bf16 bf16x4 __attribute__((ext_vector_type(4)));
typedef __bf16 bf16x8 __attribute__((ext_vector_type(8)));
typedef float f32x4 __attribute__((ext_vector_type(4)));

#define MFMA16(a, b, c) __builtin_amdgcn_mfma_f32_16x16x32_bf16((a), (b), (c), 0, 0, 0)

constexpr int EMB = 1024;
constexpr int SEQ = 2048;
constexpr int BATCH = 2;
constexpr int NTOK = BATCH * SEQ;   // 4096
constexpr int FFN = 4 * EMB;        // 4096
constexpr int HEADS = 16;
constexpr int HDIM = 64;

// q pre-scale: 1/sqrt(64) * log2(e)  (softmax runs in exp2 domain)
#define QSCALE 0.18033688011112042f

// async 16B global -> LDS (wave-uniform base + lane*16 destination)
__device__ __forceinline__ void gload16(const void* g, void* l) {
    __builtin_amdgcn_global_load_lds(
        (const __attribute__((address_space(1))) void*)g,
        (__attribute__((address_space(3))) void*)l,
        16, 0, 0);
}

// ---------------- LayerNorm: fp32 in -> bf16 out --------------------------
__global__ __launch_bounds__(256) void ln_kernel(const float* __restrict__ x,
                                                 const float* __restrict__ g,
                                                 const float* __restrict__ b,
                                                 bf16* __restrict__ out) {
    int row = blockIdx.x;
    int t = threadIdx.x;
    float4 v = reinterpret_cast<const float4*>(x + (size_t)row * EMB)[t];
    float s = v.x + v.y + v.z + v.w;
    float s2 = v.x * v.x + v.y * v.y + v.z * v.z + v.w * v.w;
#pragma unroll
    for (int o = 1; o < 64; o <<= 1) {
        s += __shfl_xor(s, o);
        s2 += __shfl_xor(s2, o);
    }
    __shared__ float ps[4], ps2[4];
    int w = t >> 6;
    if ((t & 63) == 0) { ps[w] = s; ps2[w] = s2; }
    __syncthreads();
    s = ps[0] + ps[1] + ps[2] + ps[3];
    s2 = ps2[0] + ps2[1] + ps2[2] + ps2[3];
    float mean = s * (1.f / EMB);
    float var = s2 * (1.f / EMB) - mean * mean;
    float rstd = rsqrtf(var + 1e-5f);
    float4 gv = reinterpret_cast<const float4*>(g)[t];
    float4 bv = reinterpret_cast<const float4*>(b)[t];
    bf16* op = out + (size_t)row * EMB + t * 4;
    op[0] = (bf16)(gv.x * (v.x - mean) * rstd + bv.x);
    op[1] = (bf16)(gv.y * (v.y - mean) * rstd + bv.y);
    op[2] = (bf16)(gv.z * (v.z - mean) * rstd + bv.z);
    op[3] = (bf16)(gv.w * (v.w - mean) * rstd + bv.w);
}

// ---------------- transpose + cast: W[K][N] f32 -> Wt[N][K] bf16 ----------
__global__ __launch_bounds__(256) void transpose_cast(const float* __restrict__ W,
                                                      bf16* __restrict__ Wt,
                                                      int K, int N) {
    __shared__ float t[32][33];
    int n0 = blockIdx.x * 32, k0 = blockIdx.y * 32;
    int tx = threadIdx.x, ty = threadIdx.y;  // 32 x 8
#pragma unroll
    for (int i = 0; i < 4; i++)
        t[ty + 8 * i][tx] = W[(size_t)(k0 + ty + 8 * i) * N + n0 + tx];
    __syncthreads();
#pragma unroll
    for (int i = 0; i < 4; i++)
        Wt[(size_t)(n0 + ty + 8 * i) * K + k0 + tx] = (bf16)t[tx][ty + 8 * i];
}

// ---------------- V transpose: [B,H,S,64] -> [B,H,64,S] bf16 --------------
__global__ __launch_bounds__(256) void vtrans(const bf16* __restrict__ v,
                                              bf16* __restrict__ vt) {
    int bh = blockIdx.y;
    int s0 = blockIdx.x * 64;
    const bf16* src = v + (size_t)bh * SEQ * HDIM + (size_t)s0 * HDIM;
    bf16* dst = vt + (size_t)bh * HDIM * SEQ + s0;
    __shared__ bf16 tile[64][72];
    int t = threadIdx.x;
    int s = t >> 2, d0 = (t & 3) * 16;
    bf16x8 a = *reinterpret_cast<const bf16x8*>(src + s * HDIM + d0);
    bf16x8 b = *reinterpret_cast<const bf16x8*>(src + s * HDIM + d0 + 8);
#pragma unroll
    for (int e = 0; e < 8; e++) {
        tile[d0 + e][s] = a[e];
        tile[d0 + 8 + e][s] = b[e];
    }
    __syncthreads();
    int d = t >> 2, c0 = (t & 3) * 16;
    bf16x8 o0 = *reinterpret_cast<const bf16x8*>(&tile[d][c0]);
    bf16x8 o1 = *reinterpret_cast<const bf16x8*>(&tile[d][c0 + 8]);
    *reinterpret_cast<bf16x8*>(dst + (size_t)d * SEQ + c0) = o0;
    *reinterpret_cast<bf16x8*>(dst + (size_t)d * SEQ + c0 + 8) = o1;
}

// ---------------- LDS-staged GEMM (m97 structure) -------------------------
// C = epi(A[M][K] @ Bt[N][K]^T), BK=32, 4 waves in 2x2, per-wave (BM/2)x(BN/2)
// MODE 0: fused QKV scatter -> bf16 q/k/v [B,H,S,64] (q scaled QSCALE)
// MODE 1: out f32 = resid + acc + bias
// MODE 2: out bf16 = gelu(acc + bias)
template <int BM, int BN, int MODE>
__global__ __launch_bounds__(256) void gemm_lds(const bf16* __restrict__ A,
                                                const bf16* __restrict__ Bt,
                                                int M, int N, int K,
                                                float* __restrict__ outF,
                                                bf16* __restrict__ outB,
                                                const float* __restrict__ bias,
                                                const float* __restrict__ resid) {
    constexpr int MR = BM / 32;              // M frags per wave
    constexpr int NR = BN / 32;              // N frags per wave
    constexpr int ACH = (BM * 64) / 4096;    // 16B chunks/thread for A tile
    constexpr int BCH = (BN * 64) / 4096;
    __shared__ bf16 sA[BM * 32];
    __shared__ bf16 sB[BN * 32];
    int t = threadIdx.x;
    int wave = t >> 6, lane = t & 63;
    int wr = wave >> 1, wc = wave & 1;
    int lr = lane & 15, lg = lane >> 4;
    int row0 = blockIdx.x * BM;
    int col0 = blockIdx.y * BN;

    // staging source pointers (advance 64B per K-step)
    const char* aS[ACH];
    const char* bS[BCH];
#pragma unroll
    for (int c = 0; c < ACH; c++) {
        int o = (t + c * 256) * 16;
        aS[c] = (const char*)A + (size_t)(row0 + (o >> 6)) * K * 2 + (o & 63);
    }
#pragma unroll
    for (int c = 0; c < BCH; c++) {
        int o = (t + c * 256) * 16;
        bS[c] = (const char*)Bt + (size_t)(col0 + (o >> 6)) * K * 2 + (o & 63);
    }

    f32x4 acc[MR][NR];
#pragma unroll
    for (int m = 0; m < MR; m++)
#pragma unroll
        for (int n = 0; n < NR; n++) acc[m][n] = f32x4{0.f, 0.f, 0.f, 0.f};

    for (int k0 = 0; k0 < K; k0 += 32) {
        __syncthreads();
#pragma unroll
        for (int c = 0; c < ACH; c++)
            gload16(aS[c], (char*)sA + (t + c * 256) * 16);
#pragma unroll
        for (int c = 0; c < BCH; c++)
            gload16(bS[c], (char*)sB + (t + c * 256) * 16);
#pragma unroll
        for (int c = 0; c < ACH; c++) aS[c] += 64;
#pragma unroll
        for (int c = 0; c < BCH; c++) bS[c] += 64;
        __syncthreads();

        bf16x8 a[MR], b[NR];
#pragma unroll
        for (int m = 0; m < MR; m++)
            a[m] = *reinterpret_cast<const bf16x8*>(
                sA + (wr * (BM / 2) + m * 16 + lr) * 32 + 8 * lg);
#pragma unroll
        for (int n = 0; n < NR; n++)
            b[n] = *reinterpret_cast<const bf16x8*>(
                sB + (wc * (BN / 2) + n * 16 + lr) * 32 + 8 * lg);
#pragma unroll
        for (int m = 0; m < MR; m++)
#pragma unroll
            for (int n = 0; n < NR; n++)
                acc[m][n] = MFMA16(a[m], b[n], acc[m][n]);
    }

#pragma unroll
    for (int m = 0; m < MR; m++) {
#pragma unroll
        for (int r = 0; r < 4; r++) {
            int row = row0 + wr * (BM / 2) + m * 16 + 4 * lg + r;
#pragma unroll
            for (int n = 0; n < NR; n++) {
                int col = col0 + wc * (BN / 2) + n * 16 + lr;
                float v = acc[m][n][r];
                if (MODE == 0) {
                    int b_ = row >> 11, s_ = row & 2047;
                    int which = col >> 10, rem = col & 1023;
                    int h_ = rem >> 6, d_ = rem & 63;
                    float sc = (which == 0) ? QSCALE : 1.0f;
                    outB[(size_t)which * (NTOK * EMB) +
                         (((size_t)(b_ * HEADS + h_) * SEQ + s_) << 6) + d_] =
                        (bf16)(v * sc);
                } else if (MODE == 1) {
                    size_t idx = (size_t)row * N + col;
                    outF[idx] = resid[idx] + v + bias[col];
                } else {
                    float u = v + bias[col];
                    float gl = 0.5f * u *
                               (1.f + tanhf(0.7978845608028654f *
                                            (u + 0.044715f * u * u * u)));
                    outB[(size_t)row * N + col] = (bf16)gl;
                }
            }
        }
    }
}

// ---------------- causal flash attention (v7) ------------------------------
// R2 fragment layout (un-swapped QK^T and PV: softmax state per-lane by r,
// zero broadcasts, DPP-only xor 1..8 reduces) + K/V^T tiles in LDS shared by
// 4 waves, double-buffered, async gload16 with XOR-granule swizzle
// (both-sides involution g ^= row&7 on 16B granules), stage-ahead pipeline
// (1 barrier/chunk). XCD-bijective swizzle; heavy-q first.
// q,k: [B,H,S,64] bf16 (q pre-scaled QSCALE); vt: [B,H,64,S]; ctx: [B,S,1024].
__global__ __launch_bounds__(256, 3) void attn_kernel(const bf16* __restrict__ q,
                                                      const bf16* __restrict__ k,
                                                      const bf16* __restrict__ vt,
                                                      bf16* __restrict__ ctx) {
    int wg = blockIdx.x;
    int wgid = (wg & 7) * 128 + (wg >> 3);   // bijective: 1024 = 8 XCD * 128
    int bh = wgid >> 5;                      // 4 heads per XCD, contiguous
    int q0 = (31 - (wgid & 31)) * 64;        // late (heavy) q-blocks first
    const bf16* qh = q + (size_t)bh * SEQ * HDIM;
    const bf16* kh = k + (size_t)bh * SEQ * HDIM;
    const bf16* vh = vt + (size_t)bh * HDIM * SEQ;  // [64][2048]
    int t = threadIdx.x;
    int wave = t >> 6, lane = t & 63;
    int lr = lane & 15, lg = lane >> 4;
    int qrow = q0 + wave * 16;

    __shared__ bf16 sK[2][64 * 64];   // [key][d], granule-swizzled
    __shared__ bf16 sV[2][64 * 64];   // [d][key], granule-swizzled
    __shared__ bf16 plds[4][16][88];  // per-wave P[q][key], stride 88

    // Q fragments (A-operand: row=q=lr, k=d)
    bf16x8 qf0 = *reinterpret_cast<const bf16x8*>(qh + (size_t)(qrow + lr) * HDIM + 8 * lg);
    bf16x8 qf1 = *reinterpret_cast<const bf16x8*>(qh + (size_t)(qrow + lr) * HDIM + 32 + 8 * lg);

    // staging: 256 threads x (2 K granules + 2 V granules) of 16B each.
    // granule G: row = G>>3, g = G&7; source column-granule = g ^ (row&7).
    int grow = t >> 3, gg = t & 7;
    const bf16* kSrc0 = kh + (size_t)grow * HDIM + ((gg ^ (grow & 7)) << 3);
    const bf16* kSrc1 = kh + (size_t)(grow + 32) * HDIM + ((gg ^ ((grow + 32) & 7)) << 3);
    const bf16* vSrc0 = vh + (size_t)grow * SEQ + ((gg ^ (grow & 7)) << 3);
    const bf16* vSrc1 = vh + (size_t)(grow + 32) * SEQ + ((gg ^ ((grow + 32) & 7)) << 3);
    char* kD0 = (char*)&sK[0][0] + wave * 1024;
    char* vD0 = (char*)&sV[0][0] + wave * 1024;

    f32x4 o[4];
#pragma unroll
    for (int n = 0; n < 4; n++) o[n] = f32x4{0.f, 0.f, 0.f, 0.f};
    float mx[4] = {-1e30f, -1e30f, -1e30f, -1e30f};
    float lsum[4] = {0.f, 0.f, 0.f, 0.f};

    int nc = q0 / 64 + 1;
    int swz = (lr & 7) << 4;
    int koff0 = (16 * lg) ^ swz;
    int koff1 = (64 + 16 * lg) ^ swz;

    // prologue: stage chunk 0 into buf 0
    gload16(kSrc0, kD0);
    gload16(kSrc1, kD0 + 4096);
    gload16(vSrc0, vD0);
    gload16(vSrc1, vD0 + 4096);
    __syncthreads();  // drains vmcnt before barrier (compiler-inserted)

    for (int c = 0; c < nc; c++) {
        int c0 = c * 64;
        // issue next chunk's stage (lands during this chunk's compute)
        if (c + 1 < nc) {
            int nb = (c + 1) & 1;
            int cn = c0 + 64;
            gload16(kSrc0 + (size_t)cn * HDIM, kD0 + nb * 8192);
            gload16(kSrc1 + (size_t)cn * HDIM, kD0 + nb * 8192 + 4096);
            gload16(vSrc0 + cn, vD0 + nb * 8192);
            gload16(vSrc1 + cn, vD0 + nb * 8192 + 4096);
        }
        const char* kb_ = (const char*)&sK[c & 1][0];
        const char* vb_ = (const char*)&sV[c & 1][0];

        // ---- QK^T: st[n] rows q=4lg+r, cols key=16n+lr ----
        f32x4 st[4];
#pragma unroll
        for (int n = 0; n < 4; n++) {
            int ro = (16 * n + lr) * 128;
            bf16x8 kf0 = *reinterpret_cast<const bf16x8*>(kb_ + ro + koff0);
            bf16x8 kf1 = *reinterpret_cast<const bf16x8*>(kb_ + ro + koff1);
            f32x4 a = f32x4{0.f, 0.f, 0.f, 0.f};
            a = MFMA16(qf0, kf0, a);
            a = MFMA16(qf1, kf1, a);
            st[n] = a;
        }

        if (c0 == q0) {  // diagonal chunk: causal mask (key > q)
#pragma unroll
            for (int n = 0; n < 4; n++)
#pragma unroll
                for (int r = 0; r < 4; r++)
                    if (c0 + n * 16 + lr > qrow + 4 * lg + r) st[n][r] = -1e30f;
        }

        // ---- online softmax: rows r, reduce over lr via DPP xor 1..8 ----
        float mn[4], scl[4], ps[4];
#pragma unroll
        for (int r = 0; r < 4; r++) {
            float mp = fmaxf(fmaxf(st[0][r], st[1][r]), fmaxf(st[2][r], st[3][r]));
#pragma unroll
            for (int off = 1; off < 16; off <<= 1) mp = fmaxf(mp, __shfl_xor(mp, off));
            mn[r] = fmaxf(mx[r], mp);
            scl[r] = __builtin_amdgcn_exp2f(mx[r] - mn[r]);
            mx[r] = mn[r];
            ps[r] = 0.f;
        }
#pragma unroll
        for (int n = 0; n < 4; n++)
#pragma unroll
            for (int r = 0; r < 4; r++) {
                float p = __builtin_amdgcn_exp2f(st[n][r] - mn[r]);
                ps[r] += p;
                plds[wave][4 * lg + r][n * 16 + lr] = (bf16)p;
            }
#pragma unroll
        for (int r = 0; r < 4; r++) {
            float s = ps[r];
#pragma unroll
            for (int off = 1; off < 16; off <<= 1) s += __shfl_xor(s, off);
            lsum[r] = lsum[r] * scl[r] + s;
        }
#pragma unroll
        for (int n = 0; n < 4; n++) {
            o[n][0] *= scl[0]; o[n][1] *= scl[1];
            o[n][2] *= scl[2]; o[n][3] *= scl[3];
        }

        // ---- PV: A = P (rows q), B = V^T tile (cols d = 16n+lr) ----
#pragma unroll
        for (int ks = 0; ks < 2; ks++) {
            bf16x8 pa = *reinterpret_cast<const bf16x8*>(
                &plds[wave][lr][ks * 32 + 8 * lg]);
            int vo = (64 * ks + 16 * lg) ^ swz;
#pragma unroll
            for (int n = 0; n < 4; n++) {
                bf16x8 vf = *reinterpret_cast<const bf16x8*>(
                    vb_ + (16 * n + lr) * 128 + vo);
                o[n] = MFMA16(pa, vf, o[n]);
            }
        }

        __syncthreads();  // drain staging vmcnt + all waves done with buf
    }

    // ---- epilogue: rows q=4lg+r, cols d=16n+lr ----
    int b_ = bh >> 4, h_ = bh & 15;
#pragma unroll
    for (int r = 0; r < 4; r++) {
        float inv = 1.f / lsum[r];
        size_t base = ((size_t)b_ * SEQ + qrow + 4 * lg + r) * EMB + h_ * HDIM;
#pragma unroll
        for (int n = 0; n < 4; n++)
            ctx[base + n * 16 + lr] = (bf16)(o[n][r] * inv);
    }
}

// ---------------- launch ---------------------------------------------------
extern "C" void kernel_launch(void* const* d_in, const int* in_sizes, int n_in,
                              void* d_out, int out_size, void* d_ws, size_t ws_size,
                              hipStream_t stream) {
    const float* x  = (const float*)d_in[0];
    const float* Wq = (const float*)d_in[1];
    const float* Wk = (const float*)d_in[2];
    const float* Wv = (const float*)d_in[3];
    const float* Wo = (const float*)d_in[4];
    const float* bo = (const float*)d_in[5];
    const float* W1 = (const float*)d_in[6];
    const float* b1 = (const float*)d_in[7];
    const float* W2 = (const float*)d_in[8];
    const float* b2 = (const float*)d_in[9];
    const float* g1 = (const float*)d_in[10];
    const float* s1 = (const float*)d_in[11];
    const float* g2 = (const float*)d_in[12];
    const float* s2 = (const float*)d_in[13];

    const size_t MB = 1ull << 20;
    char* w = (char*)d_ws;
    bf16* Wqkvt = (bf16*)(w + 0 * MB);            // [3072][1024] contiguous
    bf16* Wqt = Wqkvt;
    bf16* Wkt = (bf16*)(w + 2 * MB);
    bf16* Wvt = (bf16*)(w + 4 * MB);
    bf16* Wot = (bf16*)(w + 6 * MB);
    bf16* W1t = (bf16*)(w + 8 * MB);
    bf16* W2t = (bf16*)(w + 16 * MB);
    bf16* hbuf = (bf16*)(w + 24 * MB);            // h1 / h2 (reused)
    bf16* vtb  = (bf16*)(w + 24 * MB);            // aliases hbuf: used between QKV and LN2
    bf16* qkvb = (bf16*)(w + 32 * MB);            // q @32, k @40, v @48 MB
    bf16* qb   = (bf16*)(w + 32 * MB);
    bf16* kb   = (bf16*)(w + 40 * MB);
    bf16* vb   = (bf16*)(w + 48 * MB);
    bf16* ctxb = (bf16*)(w + 56 * MB);
    bf16* midb = (bf16*)(w + 32 * MB);            // reuses qkv after attn
    float* x1  = (float*)(w + 64 * MB);

    dim3 tb(32, 8);
    // weight transposes (fp32 -> bf16 [N][K]); Wq/Wk/Wv contiguous
    transpose_cast<<<dim3(EMB / 32, EMB / 32), tb, 0, stream>>>(Wq, Wqt, EMB, EMB);
    transpose_cast<<<dim3(EMB / 32, EMB / 32), tb, 0, stream>>>(Wk, Wkt, EMB, EMB);
    transpose_cast<<<dim3(EMB / 32, EMB / 32), tb, 0, stream>>>(Wv, Wvt, EMB, EMB);
    transpose_cast<<<dim3(EMB / 32, EMB / 32), tb, 0, stream>>>(Wo, Wot, EMB, EMB);
    transpose_cast<<<dim3(FFN / 32, EMB / 32), tb, 0, stream>>>(W1, W1t, EMB, FFN);
    transpose_cast<<<dim3(EMB / 32, FFN / 32), tb, 0, stream>>>(W2, W2t, FFN, EMB);

    // LN1
    ln_kernel<<<NTOK, 256, 0, stream>>>(x, g1, s1, hbuf);

    // fused QKV projection: [4096,1024] @ [3072,1024]^T
    gemm_lds<128, 128, 0><<<dim3(NTOK / 128, 3072 / 128), 256, 0, stream>>>(
        hbuf, Wqkvt, NTOK, 3072, EMB, nullptr, qkvb, nullptr, nullptr);

    // V -> V^T  [B,H,64,S]  (hbuf region is free until LN2)
    vtrans<<<dim3(SEQ / 64, BATCH * HEADS), 256, 0, stream>>>(vb, vtb);

    // attention v7 (shared swizzled LDS K/V tiles, stage-ahead, DPP softmax)
    attn_kernel<<<dim3(1024), 256, 0, stream>>>(qb, kb, vtb, ctxb);

    // output projection + residual -> x1 (f32)
    gemm_lds<128, 64, 1><<<dim3(NTOK / 128, EMB / 64), 256, 0, stream>>>(
        ctxb, Wot, NTOK, EMB, EMB, x1, nullptr, bo, x);

    // LN2
    ln_kernel<<<NTOK, 256, 0, stream>>>(x1, g2, s2, hbuf);

    // FFN1 + gelu -> bf16 mid
    gemm_lds<128, 128, 2><<<dim3(NTOK / 128, FFN / 128), 256, 0, stream>>>(
        hbuf, W1t, NTOK, FFN, EMB, nullptr, midb, b1, nullptr);

    // FFN2 + bias + residual -> d_out (f32)
    gemm_lds<128, 64, 1><<<dim3(NTOK / 128, EMB / 64), 256, 0, stream>>>(
        midb, W2t, NTOK, EMB, FFN, (float*)d_out, nullptr, b2, x1);
}